// Round 8
// baseline (1017.489 us; speedup 1.0000x reference)
//
#include <hip/hip_runtime.h>
#include <hip/hip_bf16.h>

// BLSTM: B=1024, T=512, V=128, H=128, HH=64, gates=256/dir.
// R8: gate-major tiles. Block = 256 thr (4 waves), 4 real batch rows, all 256
// gates. Wave w owns j in [16w,16w+16); its 4 N-tiles are the 4 LSTM gates
// (orig rows tau*64+j) -> i,f,g,o for (row,j) land in ONE thread's 4 accs:
// no gate-exchange shfl. 3 shfls/acc distribute rows 1..3 to quads 1..3 so
// each lane runs exactly one sigma/tanh chain (chip-wide trans == R7).
// Grid 512 blocks -> 2 blocks/CU with INDEPENDENT barriers (1 wave/SIMD each):
// block B issues while block A's serial chain stalls. MFMA x2 chip-wide
// (MfmaUtil was 19% - headroom). M-rows 4..15 stay zero; dummy C rows = init.

#define T_STEPS 512
#define BATCH   1024
#define VOCAB   128
#define HID     128
#define HH      64
#define NG      256
#define MB      4      // real batch rows per block

typedef __attribute__((ext_vector_type(8))) short bf16x8;
typedef __attribute__((ext_vector_type(4))) float f32x4;
typedef unsigned int  u32;
typedef unsigned short u16;

__device__ __forceinline__ float sigmoid_f(float x) {
    return 1.0f / (1.0f + __expf(-x));
}
__device__ __forceinline__ float tanh_f(float x) {
    return 1.0f - 2.0f / (__expf(2.0f * x) + 1.0f);
}
__device__ __forceinline__ u16 f2bf_rne(float f) {
    u32 u = __builtin_bit_cast(u32, f);
    u += 0x7FFFu + ((u >> 16) & 1u);
    return (u16)(u >> 16);
}
__device__ __forceinline__ float bf2f(u16 b) {
    return __builtin_bit_cast(float, ((u32)b) << 16);
}

// ---------------- Kernel 1: input-projection table, gate-major float4 ------
// tab4[(d*128+v)*64 + j] = { proj_i, proj_f, proj_g, proj_o } for hidden j
__global__ __launch_bounds__(256) void build_tab_kernel(
    const float* __restrict__ emb,
    const float* __restrict__ W_ih_f,
    const float* __restrict__ W_ih_b,
    float* __restrict__ tab4)
{
    int v = blockIdx.x, d = blockIdx.y, tid = threadIdx.x;
    int j = tid >> 2, tau = tid & 3;
    int g = tau * 64 + j;                 // original gate row
    const float* W = d ? W_ih_b : W_ih_f;
    const float4* e4 = (const float4*)(emb + v * HID);
    const float4* w4 = (const float4*)(W + g * HID);
    float acc = 0.0f;
#pragma unroll
    for (int k = 0; k < HID / 4; ++k) {
        float4 e = e4[k]; float4 w = w4[k];
        acc += e.x * w.x + e.y * w.y + e.z * w.z + e.w * w.w;
    }
    tab4[(((d * VOCAB) + v) * 64 + j) * 4 + tau] = acc;
}

// ---------------- Kernel 1b: split W_hh into bf16 hi/lo (orig order) ------
__global__ __launch_bounds__(64) void split_whh_kernel(
    const float* __restrict__ W_hh_f,
    const float* __restrict__ W_hh_b,
    u16* __restrict__ whh_hi,
    u16* __restrict__ whh_lo)
{
    int g = blockIdx.x, d = blockIdx.y, k = threadIdx.x;
    const float* W = d ? W_hh_b : W_hh_f;
    float w = W[g * HH + k];
    u16 hb = f2bf_rne(w);
    u16 lb = f2bf_rne(w - bf2f(hb));
    whh_hi[(d * NG + g) * HH + k] = hb;
    whh_lo[(d * NG + g) * HH + k] = lb;
}

// ---------------- Kernel 2: MFMA recurrence ----------------
// grid (256,2), block 256 (4 waves), 2 blocks/CU.
__global__ __launch_bounds__(256, 2) void lstm_rec_kernel(
    const int*  __restrict__ x,        // [1024][512]
    const u16*  __restrict__ whh_hi,   // [2][256][64] bf16 bits (orig order)
    const u16*  __restrict__ whh_lo,
    const float* __restrict__ tab4,    // [2][128][64] float4 (i,f,g,o)
    float* __restrict__ hfin)          // [2][1024][64]
{
    __shared__ u32 xs2[T_STEPS][MB];     // v<<6 (tab4 row index), 8 KB
    __shared__ u16 hbuf[2][2][1024];     // [pingpong][hi/lo][elem] 8 KB

    const int tid  = threadIdx.x;
    const int lane = tid & 63;
    const int wave = tid >> 6;           // 0..3
    const int quad = lane >> 4;          // 0..3
    const int m    = lane & 15;
    const int dir    = blockIdx.y;
    const int b_base = blockIdx.x * MB;

    // stage x, pre-scaled to tab4 row index (v*64)
    for (int i = tid; i < MB * T_STEPS; i += 256) {
        int bl = i >> 9, t = i & (T_STEPS - 1);
        xs2[t][bl] = ((u32)x[(b_base + bl) * T_STEPS + t]) << 6;
    }
    // zero both h buffers (M-rows 4..15 stay zero forever)
    for (int i = tid; i < 2048; i += 256) ((u32*)hbuf)[i] = 0;

    // persistent B-fragments: tile tau = gate tau, j = wave*16 + m
    const u16* WH = whh_hi + dir * NG * HH;
    const u16* WL = whh_lo + dir * NG * HH;
    bf16x8 Bh[4][2], Bl[4][2];
#pragma unroll
    for (int tau = 0; tau < 4; ++tau) {
        int grow = tau * 64 + wave * 16 + m;
#pragma unroll
        for (int kc = 0; kc < 2; ++kc) {
            Bh[tau][kc] = *(const bf16x8*)(WH + grow * HH + kc * 32 + quad * 8);
            Bl[tau][kc] = *(const bf16x8*)(WL + grow * HH + kc * 32 + quad * 8);
        }
    }

    const float4* tabD = (const float4*)tab4 + dir * VOCAB * 64;
    const int  j      = wave * 16 + m;           // my hidden unit
    // h write slot for (row=quad, k=j) in A-frag-order layout:
    const int  woff   = (wave >> 1) * 512 + ((wave & 1) * 2 + (m >> 3)) * 128
                      + quad * 8 + (m & 7);
    const int  aoff   = lane * 8;                // u16 units

    float cc = 0.f, hcur = 0.f;
    float4 I[4], J[4];

    __syncthreads();   // xs2 + hbuf init visible

    {   // prefetch step 0
        int t0 = dir ? (T_STEPS - 1) : 0;
        int4 vv = *(const int4*)&xs2[t0][0];     // broadcast
        I[0] = tabD[(u32)vv.x + j];
        I[1] = tabD[(u32)vv.y + j];
        I[2] = tabD[(u32)vv.z + j];
        I[3] = tabD[(u32)vv.w + j];
    }

    auto step = [&](const u16* rh, const u16* rl, u16* wh, u16* wl,
                    float4 (&cur)[4], float4 (&nxt)[4], int s) {
        bf16x8 Ah0 = *(const bf16x8*)(rh + aoff);
        bf16x8 Ah1 = *(const bf16x8*)(rh + 512 + aoff);
        bf16x8 Al0 = *(const bf16x8*)(rl + aoff);
        bf16x8 Al1 = *(const bf16x8*)(rl + 512 + aoff);

        // prefetch next step's tab init (overlaps MFMA + phase B + barrier)
        {
            int sn = (s + 1 < T_STEPS) ? s + 1 : s;
            int tn = dir ? (T_STEPS - 1 - sn) : sn;
            int4 vv = *(const int4*)&xs2[tn][0];  // one ds_read_b128, broadcast
            nxt[0] = tabD[(u32)vv.x + j];
            nxt[1] = tabD[(u32)vv.y + j];
            nxt[2] = tabD[(u32)vv.z + j];
            nxt[3] = tabD[(u32)vv.w + j];
        }

        // acc_tau[r] = C[row=quad*4+r][gate tau, col j]; init = tab (rows
        // mirror mod 4; dummy C rows 4..15 = init only, discarded)
        f32x4 a0 = {cur[0].x, cur[1].x, cur[2].x, cur[3].x};
        f32x4 a1 = {cur[0].y, cur[1].y, cur[2].y, cur[3].y};
        f32x4 a2 = {cur[0].z, cur[1].z, cur[2].z, cur[3].z};
        f32x4 a3 = {cur[0].w, cur[1].w, cur[2].w, cur[3].w};

        a0 = __builtin_amdgcn_mfma_f32_16x16x32_bf16(Ah0, Bh[0][0], a0, 0, 0, 0);
        a1 = __builtin_amdgcn_mfma_f32_16x16x32_bf16(Ah0, Bh[1][0], a1, 0, 0, 0);
        a2 = __builtin_amdgcn_mfma_f32_16x16x32_bf16(Ah0, Bh[2][0], a2, 0, 0, 0);
        a3 = __builtin_amdgcn_mfma_f32_16x16x32_bf16(Ah0, Bh[3][0], a3, 0, 0, 0);
        a0 = __builtin_amdgcn_mfma_f32_16x16x32_bf16(Ah1, Bh[0][1], a0, 0, 0, 0);
        a1 = __builtin_amdgcn_mfma_f32_16x16x32_bf16(Ah1, Bh[1][1], a1, 0, 0, 0);
        a2 = __builtin_amdgcn_mfma_f32_16x16x32_bf16(Ah1, Bh[2][1], a2, 0, 0, 0);
        a3 = __builtin_amdgcn_mfma_f32_16x16x32_bf16(Ah1, Bh[3][1], a3, 0, 0, 0);
        a0 = __builtin_amdgcn_mfma_f32_16x16x32_bf16(Al0, Bh[0][0], a0, 0, 0, 0);
        a1 = __builtin_amdgcn_mfma_f32_16x16x32_bf16(Al0, Bh[1][0], a1, 0, 0, 0);
        a2 = __builtin_amdgcn_mfma_f32_16x16x32_bf16(Al0, Bh[2][0], a2, 0, 0, 0);
        a3 = __builtin_amdgcn_mfma_f32_16x16x32_bf16(Al0, Bh[3][0], a3, 0, 0, 0);
        a0 = __builtin_amdgcn_mfma_f32_16x16x32_bf16(Al1, Bh[0][1], a0, 0, 0, 0);
        a1 = __builtin_amdgcn_mfma_f32_16x16x32_bf16(Al1, Bh[1][1], a1, 0, 0, 0);
        a2 = __builtin_amdgcn_mfma_f32_16x16x32_bf16(Al1, Bh[2][1], a2, 0, 0, 0);
        a3 = __builtin_amdgcn_mfma_f32_16x16x32_bf16(Al1, Bh[3][1], a3, 0, 0, 0);
        a0 = __builtin_amdgcn_mfma_f32_16x16x32_bf16(Ah0, Bl[0][0], a0, 0, 0, 0);
        a1 = __builtin_amdgcn_mfma_f32_16x16x32_bf16(Ah0, Bl[1][0], a1, 0, 0, 0);
        a2 = __builtin_amdgcn_mfma_f32_16x16x32_bf16(Ah0, Bl[2][0], a2, 0, 0, 0);
        a3 = __builtin_amdgcn_mfma_f32_16x16x32_bf16(Ah0, Bl[3][0], a3, 0, 0, 0);
        a0 = __builtin_amdgcn_mfma_f32_16x16x32_bf16(Ah1, Bl[0][1], a0, 0, 0, 0);
        a1 = __builtin_amdgcn_mfma_f32_16x16x32_bf16(Ah1, Bl[1][1], a1, 0, 0, 0);
        a2 = __builtin_amdgcn_mfma_f32_16x16x32_bf16(Ah1, Bl[2][1], a2, 0, 0, 0);
        a3 = __builtin_amdgcn_mfma_f32_16x16x32_bf16(Ah1, Bl[3][1], a3, 0, 0, 0);

        // distribute rows 1..3 (from quad0's accs) to quads 1..3
        float i16 = __shfl_xor(a0[1], 16), i32 = __shfl_xor(a0[2], 32), i48 = __shfl_xor(a0[3], 48);
        float f16 = __shfl_xor(a1[1], 16), f32_ = __shfl_xor(a1[2], 32), f48 = __shfl_xor(a1[3], 48);
        float g16 = __shfl_xor(a2[1], 16), g32 = __shfl_xor(a2[2], 32), g48 = __shfl_xor(a2[3], 48);
        float o16 = __shfl_xor(a3[1], 16), o32 = __shfl_xor(a3[2], 32), o48 = __shfl_xor(a3[3], 48);

        float gi = (quad == 0) ? a0[0] : (quad == 1) ? i16 : (quad == 2) ? i32 : i48;
        float gf = (quad == 0) ? a1[0] : (quad == 1) ? f16 : (quad == 2) ? f32_ : f48;
        float gg = (quad == 0) ? a2[0] : (quad == 1) ? g16 : (quad == 2) ? g32 : g48;
        float go = (quad == 0) ? a3[0] : (quad == 1) ? o16 : (quad == 2) ? o32 : o48;

        // my (row=quad, j): one LSTM chain per lane
        cc   = sigmoid_f(gf) * cc + sigmoid_f(gi) * tanh_f(gg);
        hcur = sigmoid_f(go) * tanh_f(cc);

        u16 hh = f2bf_rne(hcur);
        u16 hl = f2bf_rne(hcur - bf2f(hh));
        wh[woff] = hh;
        wl[woff] = hl;
    };

    for (int it = 0; it < T_STEPS / 2; ++it) {
        step(hbuf[0][0], hbuf[0][1], hbuf[1][0], hbuf[1][1], I, J, 2 * it);
        __syncthreads();
        step(hbuf[1][0], hbuf[1][1], hbuf[0][0], hbuf[0][1], J, I, 2 * it + 1);
        __syncthreads();
    }

    // every thread owns exactly one (row=quad, j)
    hfin[(dir * BATCH + b_base + quad) * HH + j] = hcur;
}

// ---------------- Kernel 3: final FC ----------------
__global__ __launch_bounds__(128) void fc_kernel(
    const float* __restrict__ hfin,
    const float* __restrict__ W_fc,
    const float* __restrict__ b_fc,
    float* __restrict__ out)
{
    int b = blockIdx.x;
    int v = threadIdx.x;
    __shared__ float hid[HID];
    if (v < HH) hid[v] = hfin[(0 * BATCH + b) * HH + v];
    else        hid[v] = hfin[(1 * BATCH + b) * HH + (v - HH)];
    __syncthreads();
    const float4* w4 = (const float4*)(W_fc + v * HID);
    const float4* h4 = (const float4*)hid;
    float acc = b_fc[v];
#pragma unroll
    for (int k = 0; k < HID / 4; ++k) {
        float4 w = w4[k]; float4 h = h4[k];
        acc += w.x * h.x + w.y * h.y + w.z * h.z + w.w * h.w;
    }
    out[b * HID + v] = acc;
}

extern "C" void kernel_launch(void* const* d_in, const int* in_sizes, int n_in,
                              void* d_out, int out_size, void* d_ws, size_t ws_size,
                              hipStream_t stream) {
    const int*   x      = (const int*)d_in[0];
    // d_in[1] = lengths : unused by the reference
    const float* emb    = (const float*)d_in[2];
    const float* W_ih_f = (const float*)d_in[3];
    const float* W_hh_f = (const float*)d_in[4];
    const float* W_ih_b = (const float*)d_in[5];
    const float* W_hh_b = (const float*)d_in[6];
    const float* W_fc   = (const float*)d_in[7];
    const float* b_fc   = (const float*)d_in[8];
    float* out = (float*)d_out;

    float* tab4   = (float*)d_ws;                         // 65536 f32
    u16*   whh_hi = (u16*)(tab4 + 2 * VOCAB * NG);        // 32768 u16
    u16*   whh_lo = whh_hi + 2 * NG * HH;                 // 32768 u16
    float* hfin   = (float*)(whh_lo + 2 * NG * HH);       // 131072 f32

    build_tab_kernel<<<dim3(VOCAB, 2), 256, 0, stream>>>(emb, W_ih_f, W_ih_b, tab4);
    split_whh_kernel<<<dim3(NG, 2), 64, 0, stream>>>(W_hh_f, W_hh_b, whh_hi, whh_lo);
    lstm_rec_kernel<<<dim3(BATCH / MB, 2), 256, 0, stream>>>(x, whh_hi, whh_lo, tab4, hfin);
    fc_kernel<<<dim3(BATCH), 128, 0, stream>>>(hfin, W_fc, b_fc, out);
}

// Round 9
// 394.041 us; speedup vs baseline: 2.5822x; 2.5822x over previous
//
#include <hip/hip_runtime.h>
#include <hip/hip_bf16.h>

// BLSTM: B=1024, T=512, V=128, H=128, HH=64, gates=256/dir.
// R9: LDS-pipe-throughput attack. R7 measured 2213 cyc/step with only ~580
// issue-cyc; per-CU DS traffic was ~58 KB/step (~680 cyc at 85 B/cyc) — the
// A-frag broadcast (8 waves x 4 KB of the SAME M-tile) dominated.
//  - pure bf16 recurrence GEMM: drop W_lo AND h_lo terms. 4 MFMAs/step
//    (was 12), A-reads 4->2, one h buffer, one write/lane.
//  - xor8 gate exchange via DPP row_ror:8 (VALU, free) instead of DS shfl.
//  - tab stays f32 (input projection exact), RNE bf16 rounding everywhere.
// Skeleton unchanged from R7: MB=8, 8 waves, 1 barrier/step, conflict-free
// A-frag-order h layout, xor32 ships row-B so each lane runs ONE sigma chain.

#define T_STEPS 512
#define BATCH   1024
#define VOCAB   128
#define HID     128
#define HH      64
#define NG      256
#define MB      8      // real batch rows per block

typedef __attribute__((ext_vector_type(8))) short bf16x8;
typedef __attribute__((ext_vector_type(4))) float f32x4;
typedef unsigned int  u32;
typedef unsigned short u16;

__device__ __forceinline__ float sigmoid_f(float x) {
    return 1.0f / (1.0f + __expf(-x));
}
__device__ __forceinline__ float tanh_f(float x) {
    return 1.0f - 2.0f / (__expf(2.0f * x) + 1.0f);
}
__device__ __forceinline__ u16 f2bf_rne(float f) {
    u32 u = __builtin_bit_cast(u32, f);
    u += 0x7FFFu + ((u >> 16) & 1u);
    return (u16)(u >> 16);
}
// lane^8 within each 16-lane row == DPP row_ror:8 (VALU, no DS round trip)
__device__ __forceinline__ float dpp_xor8(float v) {
    int i = __builtin_bit_cast(int, v);
    i = __builtin_amdgcn_mov_dpp(i, 0x128, 0xF, 0xF, true);
    return __builtin_bit_cast(float, i);
}

// permuted gate column c (0..255) -> original gate row g
__device__ __forceinline__ int perm_gate(int c) {
    int tile = c >> 7, rest = c & 127, w = rest >> 4, m = rest & 15;
    return (m < 8) ? (tile * 128 + w * 8 + m)
                   : (tile * 128 + 64 + w * 8 + (m - 8));
}

// ---------------- Kernel 1: input-projection tables, float2-pair layout ----
__global__ __launch_bounds__(256) void build_tab_kernel(
    const float* __restrict__ emb,
    const float* __restrict__ W_ih_f,
    const float* __restrict__ W_ih_b,
    float* __restrict__ tab2)
{
    int v = blockIdx.x, d = blockIdx.y, gp = threadIdx.x;
    int tile = gp >> 7, c0 = gp & 127;
    int g = perm_gate(tile * 128 + c0);
    const float* W = d ? W_ih_b : W_ih_f;
    const float4* e4 = (const float4*)(emb + v * HID);
    const float4* w4 = (const float4*)(W + g * HID);
    float acc = 0.0f;
#pragma unroll
    for (int k = 0; k < HID / 4; ++k) {
        float4 e = e4[k]; float4 w = w4[k];
        acc += e.x * w.x + e.y * w.y + e.z * w.z + e.w * w.w;
    }
    tab2[((d * VOCAB + v) * 128 + c0) * 2 + tile] = acc;
}

// ---------------- Kernel 1b: convert W_hh to bf16 (orig order) ------------
__global__ __launch_bounds__(64) void conv_whh_kernel(
    const float* __restrict__ W_hh_f,
    const float* __restrict__ W_hh_b,
    u16* __restrict__ whh_bf)
{
    int g = blockIdx.x, d = blockIdx.y, k = threadIdx.x;
    const float* W = d ? W_hh_b : W_hh_f;
    whh_bf[(d * NG + g) * HH + k] = f2bf_rne(W[g * HH + k]);
}

// ---------------- Kernel 2: MFMA recurrence ----------------
// grid (128,2), block 512 (8 waves), 1 block/CU.
__global__ __launch_bounds__(512, 2) void lstm_rec_kernel(
    const int*  __restrict__ x,        // [1024][512]
    const u16*  __restrict__ whh_bf,   // [2][256][64] bf16 bits (orig order)
    const float* __restrict__ tab2,    // [2][128][128] float2 pairs, permuted
    float* __restrict__ hfin)          // [2][1024][64]
{
    __shared__ u32 xs2[T_STEPS][MB];     // v*128 (pair index), 16 KB
    __shared__ u16 hbuf[2][1024];        // [pingpong][elem], 4 KB

    const int tid  = threadIdx.x;
    const int lane = tid & 63;
    const int wave = tid >> 6;           // 0..7
    const int quad = lane >> 4;          // 0..3
    const int m    = lane & 15;
    const int dir    = blockIdx.y;
    const int b_base = blockIdx.x * MB;

    // stage x, pre-scaled to tab2 pair index (v*128)
    for (int i = tid; i < MB * T_STEPS; i += 512) {
        int bl = i >> 9, t = i & (T_STEPS - 1);
        xs2[t][bl] = ((u32)x[(b_base + bl) * T_STEPS + t]) << 7;
    }
    // zero both h buffers (M-rows 8..15 stay zero forever)
    for (int i = tid; i < 1024; i += 512) ((u32*)hbuf)[i] = 0;

    // persistent B-fragments (4 x 16B = 16 regs; AGPR-eligible), permuted rows
    const u16* WB = whh_bf + dir * NG * HH;
    bf16x8 Bh[2][2];
#pragma unroll
    for (int tile = 0; tile < 2; ++tile) {
        int grow = perm_gate(tile * 128 + wave * 16 + m);
#pragma unroll
        for (int kc = 0; kc < 2; ++kc)
            Bh[tile][kc] = *(const bf16x8*)(WB + grow * HH + kc * 32 + quad * 8);
    }

    const float2* tabD = (const float2*)tab2 + dir * VOCAB * 128;
    const int  c0      = wave * 16 + m;          // pair-column 0..127
    const bool lohalf  = (m < 8);
    const bool hiw     = (lane >= 32);
    // the ONE real row this lane finalizes in phase B:
    const int  row     = 4 * (quad & 1) + (lohalf ? 0 : 2) + (quad >> 1);
    const int  wbase   = (wave >> 2) * 512 + (wave & 3) * 128 + (m & 7);
    const int  woff    = wbase + row * 8;
    const int  aoff    = lane * 8;               // u16 units
    const int  xrow    = (quad & 1) * 4;         // xs2 sub-row for my 4 C-rows

    float cc = 0.f, hcur = 0.f;
    float I0[4], I1[4], J0[4], J1[4];

    __syncthreads();   // xs2 + hbuf init visible

    {   // prefetch step 0
        int t0 = dir ? (T_STEPS - 1) : 0;
        int4 vv = *(const int4*)&xs2[t0][xrow];
        float2 p0 = tabD[(u32)vv.x + c0];
        float2 p1 = tabD[(u32)vv.y + c0];
        float2 p2 = tabD[(u32)vv.z + c0];
        float2 p3 = tabD[(u32)vv.w + c0];
        I0[0] = p0.x; I1[0] = p0.y;
        I0[1] = p1.x; I1[1] = p1.y;
        I0[2] = p2.x; I1[2] = p2.y;
        I0[3] = p3.x; I1[3] = p3.y;
    }

    auto step = [&](const u16* rh, u16* wh,
                    float (&cur0)[4], float (&cur1)[4],
                    float (&nx0)[4], float (&nx1)[4], int s) {
        bf16x8 Ah0 = *(const bf16x8*)(rh + aoff);
        bf16x8 Ah1 = *(const bf16x8*)(rh + 512 + aoff);

        // prefetch next step's tab init (overlaps MFMA + phase B)
        {
            int sn = (s + 1 < T_STEPS) ? s + 1 : s;
            int tn = dir ? (T_STEPS - 1 - sn) : sn;
            int4 vv = *(const int4*)&xs2[tn][xrow];   // one ds_read_b128
            float2 p0 = tabD[(u32)vv.x + c0];
            float2 p1 = tabD[(u32)vv.y + c0];
            float2 p2 = tabD[(u32)vv.z + c0];
            float2 p3 = tabD[(u32)vv.w + c0];
            nx0[0] = p0.x; nx1[0] = p0.y;
            nx0[1] = p1.x; nx1[1] = p1.y;
            nx0[2] = p2.x; nx1[2] = p2.y;
            nx0[3] = p3.x; nx1[3] = p3.y;
        }

        // pure-bf16 gate GEMM: 4 MFMAs, dependent depth 2
        f32x4 acc0 = {cur0[0], cur0[1], cur0[2], cur0[3]};
        f32x4 acc1 = {cur1[0], cur1[1], cur1[2], cur1[3]};
        acc0 = __builtin_amdgcn_mfma_f32_16x16x32_bf16(Ah0, Bh[0][0], acc0, 0, 0, 0);
        acc1 = __builtin_amdgcn_mfma_f32_16x16x32_bf16(Ah0, Bh[1][0], acc1, 0, 0, 0);
        acc0 = __builtin_amdgcn_mfma_f32_16x16x32_bf16(Ah1, Bh[0][1], acc0, 0, 0, 0);
        acc1 = __builtin_amdgcn_mfma_f32_16x16x32_bf16(Ah1, Bh[1][1], acc1, 0, 0, 0);

        // xor8 exchange via DPP (VALU): complete (i,f,g,o) for my 2 C rows
        float e0 = dpp_xor8(lohalf ? acc0[2] : acc0[0]);
        float e1 = dpp_xor8(lohalf ? acc0[3] : acc0[1]);
        float e2 = dpp_xor8(lohalf ? acc1[2] : acc1[0]);
        float e3 = dpp_xor8(lohalf ? acc1[3] : acc1[1]);

        float i0 = lohalf ? acc0[0] : e0;    // row r0
        float f0 = lohalf ? e0 : acc0[2];
        float g0 = lohalf ? acc1[0] : e2;
        float o0 = lohalf ? e2 : acc1[2];
        float i1 = lohalf ? acc0[1] : e1;    // row r0+1
        float f1 = lohalf ? e1 : acc0[3];
        float g1 = lohalf ? acc1[1] : e3;
        float o1 = lohalf ? e3 : acc1[3];

        // xor32: ship row-B gates; lanes>=32 take over partner's row r0+1
        float ri = __shfl_xor(i1, 32);
        float rf = __shfl_xor(f1, 32);
        float rg = __shfl_xor(g1, 32);
        float ro = __shfl_xor(o1, 32);
        float gi = hiw ? ri : i0;
        float gf = hiw ? rf : f0;
        float gg = hiw ? rg : g0;
        float go = hiw ? ro : o0;

        cc   = sigmoid_f(gf) * cc + sigmoid_f(gi) * tanh_f(gg);
        hcur = sigmoid_f(go) * tanh_f(cc);

        wh[woff] = f2bf_rne(hcur);
    };

    for (int it = 0; it < T_STEPS / 2; ++it) {
        step(hbuf[0], hbuf[1], I0, I1, J0, J1, 2 * it);
        __syncthreads();
        step(hbuf[1], hbuf[0], J0, J1, I0, I1, 2 * it + 1);
        __syncthreads();
    }

    // every thread owns exactly one (b, j)
    {
        int j = wave * 8 + (m & 7);
        hfin[(dir * BATCH + b_base + row) * HH + j] = hcur;
    }
}

// ---------------- Kernel 3: final FC ----------------
__global__ __launch_bounds__(128) void fc_kernel(
    const float* __restrict__ hfin,
    const float* __restrict__ W_fc,
    const float* __restrict__ b_fc,
    float* __restrict__ out)
{
    int b = blockIdx.x;
    int v = threadIdx.x;
    __shared__ float hid[HID];
    if (v < HH) hid[v] = hfin[(0 * BATCH + b) * HH + v];
    else        hid[v] = hfin[(1 * BATCH + b) * HH + (v - HH)];
    __syncthreads();
    const float4* w4 = (const float4*)(W_fc + v * HID);
    const float4* h4 = (const float4*)hid;
    float acc = b_fc[v];
#pragma unroll
    for (int k = 0; k < HID / 4; ++k) {
        float4 w = w4[k]; float4 h = h4[k];
        acc += w.x * h.x + w.y * h.y + w.z * h.z + w.w * h.w;
    }
    out[b * HID + v] = acc;
}

extern "C" void kernel_launch(void* const* d_in, const int* in_sizes, int n_in,
                              void* d_out, int out_size, void* d_ws, size_t ws_size,
                              hipStream_t stream) {
    const int*   x      = (const int*)d_in[0];
    // d_in[1] = lengths : unused by the reference
    const float* emb    = (const float*)d_in[2];
    const float* W_ih_f = (const float*)d_in[3];
    const float* W_hh_f = (const float*)d_in[4];
    const float* W_ih_b = (const float*)d_in[5];
    const float* W_hh_b = (const float*)d_in[6];
    const float* W_fc   = (const float*)d_in[7];
    const float* b_fc   = (const float*)d_in[8];
    float* out = (float*)d_out;

    float* tab2   = (float*)d_ws;                         // 65536 f32 (pairs)
    u16*   whh_bf = (u16*)(tab2 + 2 * VOCAB * NG);        // 32768 u16
    float* hfin   = (float*)(whh_bf + 2 * NG * HH);       // 131072 f32

    build_tab_kernel<<<dim3(VOCAB, 2), 256, 0, stream>>>(emb, W_ih_f, W_ih_b, tab2);
    conv_whh_kernel<<<dim3(NG, 2), 64, 0, stream>>>(W_hh_f, W_hh_b, whh_bf);
    lstm_rec_kernel<<<dim3(BATCH / MB, 2), 512, 0, stream>>>(x, whh_bf, tab2, hfin);
    fc_kernel<<<dim3(BATCH), 128, 0, stream>>>(hfin, W_fc, b_fc, out);
}